// Round 1
// baseline (8817.988 us; speedup 1.0000x reference)
//
#include <hip/hip_runtime.h>
#include <math.h>

#define NN 100000
#define EE 500000
#define ET 32

__device__ __forceinline__ float dot4(float4 a, float4 b){
    return fmaf(a.x,b.x, fmaf(a.y,b.y, fmaf(a.z,b.z, a.w*b.w)));
}

// ---------------- Stage 1: per-node quantum state prep -> qf (N,128) ----------------
__global__ __launch_bounds__(256) void node_kernel(
    const float* __restrict__ x,
    const float* __restrict__ sp_w, const float* __restrict__ sp_b,
    const float* __restrict__ ln1_g, const float* __restrict__ ln1_b,
    const float* __restrict__ pg,
    const float* __restrict__ amp_w, const float* __restrict__ amp_b,
    const float* __restrict__ ph_w, const float* __restrict__ ph_b,
    float* __restrict__ qf)
{
    const int tid = threadIdx.x;
    const int sub = tid >> 7;        // 2 nodes per block
    const int o   = tid & 127;
    const int n   = blockIdx.x*2 + sub;
    __shared__ float xr[2][128];
    __shared__ float qs[2][128];
    __shared__ float ap[2][128];
    __shared__ float red[4][2];

    if (o < 32) ((float4*)&xr[sub][0])[o] = ((const float4*)x)[(long)n*32 + o];
    __syncthreads();

    // y = x @ sp_w.T + sp_b
    float acc = sp_b[o];
    {
        const float4* w4 = (const float4*)(sp_w + o*128);
        const float4* xv = (const float4*)&xr[sub][0];
        #pragma unroll
        for (int k=0;k<32;k++) acc += dot4(w4[k], xv[k]);
    }
    // layernorm over 128 (2 waves per node)
    float s = acc, sq = acc*acc;
    #pragma unroll
    for (int m=1;m<64;m<<=1){ s += __shfl_xor(s,m); sq += __shfl_xor(sq,m); }
    if ((tid&63)==0){ red[tid>>6][0]=s; red[tid>>6][1]=sq; }
    __syncthreads();
    float S  = red[sub*2][0]+red[sub*2+1][0];
    float SQ = red[sub*2][1]+red[sub*2+1][1];
    float mean = S*(1.0f/128.0f);
    float rstd = rsqrtf(SQ*(1.0f/128.0f)-mean*mean + 1e-5f);
    float qv = tanhf((acc-mean)*rstd*ln1_g[o] + ln1_b[o]);
    qs[sub][o] = qv;
    __syncthreads();

    // amp (from real, threads 0..63 of sub-block) / ph (from imag, threads 64..127)
    const int o2 = o & 63;
    float a2;
    if (o < 64) {
        float r = amp_b[o2];
        const float4* w4 = (const float4*)(amp_w + o2*64);
        const float4* rv = (const float4*)&qs[sub][0];
        #pragma unroll
        for (int k=0;k<16;k++) r += dot4(w4[k], rv[k]);
        a2 = 1.0f/(1.0f+expf(-r));                       // sigmoid
    } else {
        float r = ph_b[o2];
        const float4* w4 = (const float4*)(ph_w + o2*64);
        const float4* iv = (const float4*)&qs[sub][64];
        #pragma unroll
        for (int k=0;k<16;k++) r += dot4(w4[k], iv[k]);
        a2 = tanhf(r)*3.14159265358979323846f;           // ph * pi
    }
    ap[sub][o] = a2;
    __syncthreads();
    if (o < 64) {
        float amp = ap[sub][o];
        float ph  = ap[sub][64+o];
        float pgs = 0.f;
        #pragma unroll
        for (int r=0;r<8;r++) pgs += pg[r*64 + o];       // phase_gates.sum(0)
        float ang = ph + qs[sub][o]*pgs;
        qf[(long)n*128 + o]      = amp * cosf(ang);
        qf[(long)n*128 + 64 + o] = amp * sinf(ang);
    }
}

// ---------------- Stage 2: per-edge message + scatter-add into agg (=d_out) ----------------
__global__ __launch_bounds__(512) void edge_kernel(
    const float* __restrict__ qf, const int* __restrict__ eidx,
    const float* __restrict__ ent_w, const float* __restrict__ ent_b,
    const float* __restrict__ q_w, const float* __restrict__ q_b,
    const float* __restrict__ k_w, const float* __restrict__ k_b,
    const float* __restrict__ v_w, const float* __restrict__ v_b,
    const float* __restrict__ meas_w, const float* __restrict__ meas_b,
    const float* __restrict__ out_w, const float* __restrict__ out_b,
    float* __restrict__ agg)
{
    const int tid = threadIdx.x;
    const long e0 = (long)blockIdx.x * ET;   // E = 500000 = 15625 * 32, exact
    __shared__ float xin[ET][256];   // [xi | xj]
    __shared__ float ebuf[ET][256];  // [ei | ej]
    __shared__ float msgin[ET][128]; // qm + measured
    __shared__ float sw[ET][4];
    __shared__ int tg[ET], sr[ET];

    if (tid < ET) tg[tid] = eidx[EE + e0 + tid];          // tgt = edge_index[1]
    else if (tid < 2*ET) sr[tid-ET] = eidx[e0 + (tid-ET)]; // src = edge_index[0]
    __syncthreads();
    for (int idx = tid; idx < ET*32; idx += 512) {
        int e = idx >> 5, f4 = idx & 31;
        ((float4*)&xin[e][0])[f4]   = ((const float4*)qf)[(long)tg[e]*32 + f4]; // x_i
        ((float4*)&xin[e][128])[f4] = ((const float4*)qf)[(long)sr[e]*32 + f4]; // x_j
    }
    __syncthreads();

    // ---- ent = cat(xi,xj) @ ent_w.T + ent_b  (256 outs; 2 edge-groups of 16) ----
    {
        const int o   = tid & 255;
        const int ebb = (tid >> 8) * 16;
        float acc[16];
        float b = ent_b[o];
        #pragma unroll
        for (int e=0;e<16;e++) acc[e]=b;
        const float4* w4 = (const float4*)(ent_w + o*256);
        #pragma unroll 4
        for (int k=0;k<64;k++){
            float4 w = w4[k];
            #pragma unroll
            for (int e=0;e<16;e++)
                acc[e] += dot4(w, ((const float4*)&xin[ebb+e][0])[k]);
        }
        #pragma unroll
        for (int e=0;e<16;e++) ebuf[ebb+e][o] = acc[e];
    }
    __syncthreads();

    const int o  = tid & 127;
    const int eb = (tid >> 7) * 8;   // 4 edge-groups of 8
    // ---- q = xi@q_w.T, k = xj@k_w.T, scores, softmax over 4 heads ----
    {
        float aq[8], ak[8];
        float qb = q_b[o], kb = k_b[o];
        #pragma unroll
        for (int e=0;e<8;e++){ aq[e]=qb; ak[e]=kb; }
        const float4* qw = (const float4*)(q_w + o*128);
        const float4* kw = (const float4*)(k_w + o*128);
        #pragma unroll 4
        for (int k=0;k<32;k++){
            float4 qv = qw[k], kv = kw[k];
            #pragma unroll
            for (int e=0;e<8;e++){
                aq[e] += dot4(qv, ((const float4*)&xin[eb+e][0])[k]);
                ak[e] += dot4(kv, ((const float4*)&xin[eb+e][128])[k]);
            }
        }
        #pragma unroll
        for (int e=0;e<8;e++){
            float p = aq[e]*ak[e];
            #pragma unroll
            for (int m=1;m<32;m<<=1) p += __shfl_xor(p,m);  // sum over 32 dims of head
            if ((o&31)==0) sw[eb+e][o>>5] = p * 0.17677669529663688f; // /sqrt(32)
        }
    }
    __syncthreads();
    if (tid < ET) {
        float s0=sw[tid][0], s1=sw[tid][1], s2=sw[tid][2], s3=sw[tid][3];
        float mx = fmaxf(fmaxf(s0,s1),fmaxf(s2,s3));
        s0=expf(s0-mx); s1=expf(s1-mx); s2=expf(s2-mx); s3=expf(s3-mx);
        float inv = 1.0f/(s0+s1+s2+s3);
        sw[tid][0]=s0*inv; sw[tid][1]=s1*inv; sw[tid][2]=s2*inv; sw[tid][3]=s3*inv;
    }
    __syncthreads();

    float macc[8];
    // ---- v = xj@v_w.T ; qm = softmax_w * v ----
    {
        float av[8];
        float vb = v_b[o];
        #pragma unroll
        for (int e=0;e<8;e++) av[e]=vb;
        const float4* vw = (const float4*)(v_w + o*128);
        #pragma unroll 4
        for (int k=0;k<32;k++){
            float4 vv = vw[k];
            #pragma unroll
            for (int e=0;e<8;e++)
                av[e] += dot4(vv, ((const float4*)&xin[eb+e][128])[k]);
        }
        const int h = o>>5;
        #pragma unroll
        for (int e=0;e<8;e++) macc[e] = sw[eb+e][h]*av[e];
    }
    // ---- measured = mean_k (ei@Wk.T + bk)(ej@Wk.T + bk) ----
    #pragma unroll 1
    for (int kk=0;kk<4;kk++){
        float ai[8], aj[8];
        float mb = meas_b[kk*128+o];
        #pragma unroll
        for (int e=0;e<8;e++){ ai[e]=mb; aj[e]=mb; }
        const float4* mw = (const float4*)(meas_w + (size_t)(kk*128+o)*128);
        #pragma unroll 4
        for (int k=0;k<32;k++){
            float4 w = mw[k];
            #pragma unroll
            for (int e=0;e<8;e++){
                ai[e] += dot4(w, ((const float4*)&ebuf[eb+e][0])[k]);
                aj[e] += dot4(w, ((const float4*)&ebuf[eb+e][128])[k]);
            }
        }
        #pragma unroll
        for (int e=0;e<8;e++) macc[e] += 0.25f*ai[e]*aj[e];
    }
    #pragma unroll
    for (int e=0;e<8;e++) msgin[eb+e][o] = macc[e];
    __syncthreads();

    // ---- msg = (qm+measured)@out_w.T + out_b ; scatter-add by tgt ----
    {
        float ao[8];
        float ob = out_b[o];
        #pragma unroll
        for (int e=0;e<8;e++) ao[e]=ob;
        const float4* ow = (const float4*)(out_w + o*128);
        #pragma unroll 4
        for (int k=0;k<32;k++){
            float4 w = ow[k];
            #pragma unroll
            for (int e=0;e<8;e++)
                ao[e] += dot4(w, ((const float4*)&msgin[eb+e][0])[k]);
        }
        #pragma unroll
        for (int e=0;e<8;e++)
            atomicAdd(&agg[(long)tg[eb+e]*128 + o], ao[e]);
    }
}

// ---------------- Stage 3: LN + exact gelu, in place on d_out ----------------
__global__ __launch_bounds__(256) void final_kernel(
    const float* __restrict__ g2, const float* __restrict__ b2,
    float* __restrict__ io)
{
    const int lane = threadIdx.x & 63;
    const int n = blockIdx.x*4 + (threadIdx.x>>6);   // 1 wave per node
    float v0 = io[(long)n*128 + lane];
    float v1 = io[(long)n*128 + 64 + lane];
    float s = v0+v1, sq = v0*v0 + v1*v1;
    #pragma unroll
    for (int m=1;m<64;m<<=1){ s += __shfl_xor(s,m); sq += __shfl_xor(sq,m); }
    float mean = s*(1.0f/128.0f);
    float rstd = rsqrtf(sq*(1.0f/128.0f)-mean*mean+1e-5f);
    float y0 = (v0-mean)*rstd*g2[lane]    + b2[lane];
    float y1 = (v1-mean)*rstd*g2[64+lane] + b2[64+lane];
    io[(long)n*128+lane]    = 0.5f*y0*(1.0f+erff(y0*0.70710678118f));
    io[(long)n*128+64+lane] = 0.5f*y1*(1.0f+erff(y1*0.70710678118f));
}

extern "C" void kernel_launch(void* const* d_in, const int* in_sizes, int n_in,
                              void* d_out, int out_size, void* d_ws, size_t ws_size,
                              hipStream_t stream)
{
    const float* x      = (const float*)d_in[0];
    const int*   eidx   = (const int*)  d_in[1];
    const float* sp_w   = (const float*)d_in[2];
    const float* sp_b   = (const float*)d_in[3];
    const float* ln1_g  = (const float*)d_in[4];
    const float* ln1_b  = (const float*)d_in[5];
    const float* pg     = (const float*)d_in[6];
    const float* amp_w  = (const float*)d_in[7];
    const float* amp_b  = (const float*)d_in[8];
    const float* ph_w   = (const float*)d_in[9];
    const float* ph_b   = (const float*)d_in[10];
    const float* ent_w  = (const float*)d_in[11];
    const float* ent_b  = (const float*)d_in[12];
    const float* q_w    = (const float*)d_in[13];
    const float* q_b    = (const float*)d_in[14];
    const float* k_w    = (const float*)d_in[15];
    const float* k_b    = (const float*)d_in[16];
    const float* v_w    = (const float*)d_in[17];
    const float* v_b    = (const float*)d_in[18];
    const float* meas_w = (const float*)d_in[19];
    const float* meas_b = (const float*)d_in[20];
    const float* out_w  = (const float*)d_in[21];
    const float* out_b  = (const float*)d_in[22];
    const float* ln2_g  = (const float*)d_in[23];
    const float* ln2_b  = (const float*)d_in[24];

    float* qf  = (float*)d_ws;          // N*128 f32 = 51.2 MB scratch
    float* agg = (float*)d_out;         // accumulate messages directly in d_out

    hipMemsetAsync(d_out, 0, (size_t)NN*128*sizeof(float), stream);
    node_kernel<<<NN/2, 256, 0, stream>>>(x, sp_w, sp_b, ln1_g, ln1_b, pg,
                                          amp_w, amp_b, ph_w, ph_b, qf);
    edge_kernel<<<EE/ET, 512, 0, stream>>>(qf, eidx,
                                           ent_w, ent_b, q_w, q_b, k_w, k_b, v_w, v_b,
                                           meas_w, meas_b, out_w, out_b, agg);
    final_kernel<<<NN/4, 256, 0, stream>>>(ln2_g, ln2_b, (float*)d_out);
}

// Round 2
// 2185.261 us; speedup vs baseline: 4.0352x; 4.0352x over previous
//
#include <hip/hip_runtime.h>
#include <math.h>

#define NN 100000
#define EE 500000
#define ET 64

typedef __attribute__((ext_vector_type(8))) short short8;
typedef __attribute__((ext_vector_type(4))) float f32x4;

// LDS chunk swizzle: 16B chunks, XOR row&7 into chunk index (T2, §6 G4)
#define C32(row, ch) (((row)<<5) + ((ch) ^ ((row)&7)))           // [*][256] bf16 buffers
#define E32(row, col) ((C32((row),(col)>>3)<<3) + ((col)&7))
#define C16(row, ch) (((row)<<4) + ((ch) ^ ((row)&7)))           // [*][128] bf16 buffer

__device__ __forceinline__ f32x4 mfma16(short8 a, short8 b, f32x4 c){
    return __builtin_amdgcn_mfma_f32_16x16x32_bf16(a, b, c, 0, 0, 0);
}
__device__ __forceinline__ short f2bf(float f){
    union { float f; unsigned u; } v; v.f = f;
    unsigned r = v.u + 0x7fffu + ((v.u >> 16) & 1u);
    return (short)(r >> 16);
}
__device__ __forceinline__ float bf2f(short s){
    union { unsigned u; float f; } v; v.u = ((unsigned)(unsigned short)s) << 16;
    return v.f;
}
// B fragment: W row-major [O][K] bf16; lane -> col=lane&15 (+16*ct), k=(lane>>4)*8..+7
__device__ __forceinline__ short8 bfrag(const short* __restrict__ W, int K, int ct, int ks, int lane){
    return *(const short8*)(W + (long)(ct*16 + (lane&15))*K + ks*32 + (lane>>4)*8);
}

__device__ __forceinline__ float dot4f(float4 a, float4 b){
    return fmaf(a.x,b.x, fmaf(a.y,b.y, fmaf(a.z,b.z, a.w*b.w)));
}

// ---------------- Prep: convert all edge-stage weights to bf16 in ws ----------------
__global__ __launch_bounds__(256) void prep_kernel(
    const float* __restrict__ ent_w, const float* __restrict__ q_w,
    const float* __restrict__ k_w,   const float* __restrict__ v_w,
    const float* __restrict__ meas_w,const float* __restrict__ out_w,
    short* __restrict__ dst)
{
    int i = blockIdx.x*256 + threadIdx.x;   // 196608 total
    float v;
    if      (i <  65536) v = ent_w[i];
    else if (i <  81920) v = q_w[i-65536];
    else if (i <  98304) v = k_w[i-81920];
    else if (i < 114688) v = v_w[i-98304];
    else if (i < 180224) v = meas_w[i-114688];
    else                 v = out_w[i-180224];
    dst[i] = f2bf(v);
}

// ---------------- Stage 1: per-node quantum state prep -> qfb (N,128) bf16 ----------------
__global__ __launch_bounds__(256) void node_kernel(
    const float* __restrict__ x,
    const float* __restrict__ sp_w, const float* __restrict__ sp_b,
    const float* __restrict__ ln1_g, const float* __restrict__ ln1_b,
    const float* __restrict__ pg,
    const float* __restrict__ amp_w, const float* __restrict__ amp_b,
    const float* __restrict__ ph_w, const float* __restrict__ ph_b,
    short* __restrict__ qfb)
{
    const int tid = threadIdx.x;
    const int sub = tid >> 7;        // 2 nodes per block
    const int o   = tid & 127;
    const int n   = blockIdx.x*2 + sub;
    __shared__ float xr[2][128];
    __shared__ float qs[2][128];
    __shared__ float ap[2][128];
    __shared__ float red[4][2];

    if (o < 32) ((float4*)&xr[sub][0])[o] = ((const float4*)x)[(long)n*32 + o];
    __syncthreads();

    float acc = sp_b[o];
    {
        const float4* w4 = (const float4*)(sp_w + o*128);
        const float4* xv = (const float4*)&xr[sub][0];
        #pragma unroll
        for (int k=0;k<32;k++) acc += dot4f(w4[k], xv[k]);
    }
    float s = acc, sq = acc*acc;
    #pragma unroll
    for (int m=1;m<64;m<<=1){ s += __shfl_xor(s,m); sq += __shfl_xor(sq,m); }
    if ((tid&63)==0){ red[tid>>6][0]=s; red[tid>>6][1]=sq; }
    __syncthreads();
    float S  = red[sub*2][0]+red[sub*2+1][0];
    float SQ = red[sub*2][1]+red[sub*2+1][1];
    float mean = S*(1.0f/128.0f);
    float rstd = rsqrtf(SQ*(1.0f/128.0f)-mean*mean + 1e-5f);
    float qv = tanhf((acc-mean)*rstd*ln1_g[o] + ln1_b[o]);
    qs[sub][o] = qv;
    __syncthreads();

    const int o2 = o & 63;
    float a2;
    if (o < 64) {
        float r = amp_b[o2];
        const float4* w4 = (const float4*)(amp_w + o2*64);
        const float4* rv = (const float4*)&qs[sub][0];
        #pragma unroll
        for (int k=0;k<16;k++) r += dot4f(w4[k], rv[k]);
        a2 = 1.0f/(1.0f+expf(-r));
    } else {
        float r = ph_b[o2];
        const float4* w4 = (const float4*)(ph_w + o2*64);
        const float4* iv = (const float4*)&qs[sub][64];
        #pragma unroll
        for (int k=0;k<16;k++) r += dot4f(w4[k], iv[k]);
        a2 = tanhf(r)*3.14159265358979323846f;
    }
    ap[sub][o] = a2;
    __syncthreads();
    if (o < 64) {
        float amp = ap[sub][o];
        float ph  = ap[sub][64+o];
        float pgs = 0.f;
        #pragma unroll
        for (int r=0;r<8;r++) pgs += pg[r*64 + o];
        float ang = ph + qs[sub][o]*pgs;
        qfb[(long)n*128 + o]      = f2bf(amp * cosf(ang));
        qfb[(long)n*128 + 64 + o] = f2bf(amp * sinf(ang));
    }
}

// ---------------- Stage 2: per-edge MFMA message + scatter-add ----------------
__global__ __launch_bounds__(512, 4) void edge_kernel(
    const short* __restrict__ qfb, const int* __restrict__ eidx,
    const short* __restrict__ wE, const float* __restrict__ ent_b,
    const short* __restrict__ wQ, const float* __restrict__ q_b,
    const short* __restrict__ wK, const float* __restrict__ k_b,
    const short* __restrict__ wV, const float* __restrict__ v_b,
    const short* __restrict__ wM, const float* __restrict__ meas_b,
    const short* __restrict__ wO, const float* __restrict__ out_b,
    float* __restrict__ agg)
{
    __shared__ short xin[ET][256];   // [xi|xj] bf16, swizzled; later reused as msgb[64][128]
    __shared__ short qkb[ET][256];   // [q|k] bf16, swizzled; later reused as ebuf [ei|ej]
    __shared__ float swv[ET][4];
    __shared__ int tg[ET];
    __shared__ int srr[ET];

    const int tid  = threadIdx.x;
    const int lane = tid & 63;
    const int w    = tid >> 6;            // wave 0..7
    const long e0  = (long)blockIdx.x * ET;
    const int l15  = lane & 15;
    const int lj   = (lane >> 4) << 2;    // row offset within 16-tile: +j (j=0..3)

    if (tid < ET) {
        long ee = e0 + tid;
        if (ee >= EE) ee = EE - 1;
        tg[tid]  = eidx[EE + ee];    // tgt
        srr[tid] = eidx[ee];         // src
    }
    __syncthreads();

    // gather x_i (cols 0..127) / x_j (128..255), 16B chunks, swizzled store
    for (int t = tid; t < ET*32; t += 512) {
        int e = t >> 5, c8 = t & 31;
        int node = (c8 < 16) ? tg[e] : srr[e];
        short8 val = ((const short8*)(qfb + (long)node*128))[c8 & 15];
        ((short8*)&xin[0][0])[C32(e, c8)] = val;
    }
    __syncthreads();

    const short8* xinv = (const short8*)&xin[0][0];
    short* qk1 = &qkb[0][0];

    // ---- Phase QK: q = xi@Wq^T, k = xj@Wk^T -> qkb bf16 ----
    {
        f32x4 aq[4], ak[4];
        #pragma unroll
        for (int r=0;r<4;r++){ aq[r]=(f32x4){0,0,0,0}; ak[r]=(f32x4){0,0,0,0}; }
        #pragma unroll
        for (int ks=0; ks<4; ks++){
            short8 bq = bfrag(wQ,128,w,ks,lane);
            short8 bk = bfrag(wK,128,w,ks,lane);
            #pragma unroll
            for (int r=0;r<4;r++){
                short8 ai = xinv[C32(r*16+l15, (ks<<2)+(lane>>4))];
                short8 aj = xinv[C32(r*16+l15, 16+(ks<<2)+(lane>>4))];
                aq[r] = mfma16(ai, bq, aq[r]);
                ak[r] = mfma16(aj, bk, ak[r]);
            }
        }
        const int col = (w<<4) + l15;
        float qbias = q_b[col], kbias = k_b[col];
        #pragma unroll
        for (int r=0;r<4;r++){
            #pragma unroll
            for (int j=0;j<4;j++){
                int row = r*16 + lj + j;
                qk1[E32(row, col)]     = f2bf(aq[r][j] + qbias);
                qk1[E32(row, 128+col)] = f2bf(ak[r][j] + kbias);
            }
        }
    }
    __syncthreads();

    // ---- scores + softmax over 4 heads ----
    if (tid < 256){
        int e = tid >> 2, h = tid & 3;
        float s = 0.f;
        #pragma unroll
        for (int d=0; d<32; d++)
            s += bf2f(qk1[E32(e, h*32+d)]) * bf2f(qk1[E32(e, 128+h*32+d)]);
        swv[e][h] = s * 0.17677669529663688f;   // 1/sqrt(32)
    }
    __syncthreads();
    if (tid < ET){
        float s0=swv[tid][0], s1=swv[tid][1], s2=swv[tid][2], s3=swv[tid][3];
        float mx = fmaxf(fmaxf(s0,s1),fmaxf(s2,s3));
        s0=expf(s0-mx); s1=expf(s1-mx); s2=expf(s2-mx); s3=expf(s3-mx);
        float inv = 1.0f/(s0+s1+s2+s3);
        swv[tid][0]=s0*inv; swv[tid][1]=s1*inv; swv[tid][2]=s2*inv; swv[tid][3]=s3*inv;
    }
    __syncthreads();

    // ---- Phase ENT: ent = [xi|xj]@We^T -> overwrite qkb as [ei|ej] bf16 ----
    {
        f32x4 a0[4], a1[4];
        #pragma unroll
        for (int r=0;r<4;r++){ a0[r]=(f32x4){0,0,0,0}; a1[r]=(f32x4){0,0,0,0}; }
        const int ct0 = 2*w, ct1 = 2*w+1;
        #pragma unroll
        for (int ks=0; ks<8; ks++){
            short8 b0 = bfrag(wE,256,ct0,ks,lane);
            short8 b1 = bfrag(wE,256,ct1,ks,lane);
            #pragma unroll
            for (int r=0;r<4;r++){
                short8 a = xinv[C32(r*16+l15, (ks<<2)+(lane>>4))];
                a0[r] = mfma16(a, b0, a0[r]);
                a1[r] = mfma16(a, b1, a1[r]);
            }
        }
        float bb0 = ent_b[ct0*16 + l15];
        float bb1 = ent_b[ct1*16 + l15];
        #pragma unroll
        for (int r=0;r<4;r++){
            #pragma unroll
            for (int j=0;j<4;j++){
                int row = r*16 + lj + j;
                qk1[E32(row, ct0*16+l15)] = f2bf(a0[r][j] + bb0);
                qk1[E32(row, ct1*16+l15)] = f2bf(a1[r][j] + bb1);
            }
        }
    }
    __syncthreads();

    // ---- Phase V: v = xj@Wv^T; qm = softmax_w * v (kept in registers) ----
    f32x4 qm[4];
    {
        #pragma unroll
        for (int r=0;r<4;r++) qm[r]=(f32x4){0,0,0,0};
        #pragma unroll
        for (int ks=0; ks<4; ks++){
            short8 bv = bfrag(wV,128,w,ks,lane);
            #pragma unroll
            for (int r=0;r<4;r++){
                short8 aj = xinv[C32(r*16+l15, 16+(ks<<2)+(lane>>4))];
                qm[r] = mfma16(aj, bv, qm[r]);
            }
        }
        float vbias = v_b[(w<<4) + l15];
        const int h = w >> 1;
        #pragma unroll
        for (int r=0;r<4;r++){
            #pragma unroll
            for (int j=0;j<4;j++){
                int row = r*16 + lj + j;
                qm[r][j] = (qm[r][j] + vbias) * swv[row][h];
            }
        }
    }

    // ---- Phase MEAS: qm += mean_kk (ei@Wm^T+b)(ej@Wm^T+b) ----
    {
        const short8* ebv = (const short8*)&qkb[0][0];
        #pragma unroll 1
        for (int kk=0; kk<4; kk++){
            f32x4 mi[4], mj[4];
            #pragma unroll
            for (int r=0;r<4;r++){ mi[r]=(f32x4){0,0,0,0}; mj[r]=(f32x4){0,0,0,0}; }
            short8 bm[4];
            const short* wMk = wM + (long)kk*128*128;
            #pragma unroll
            for (int ks=0;ks<4;ks++) bm[ks] = bfrag(wMk, 128, w, ks, lane);
            #pragma unroll
            for (int ks=0;ks<4;ks++){
                #pragma unroll
                for (int r=0;r<4;r++){
                    short8 ai = ebv[C32(r*16+l15, (ks<<2)+(lane>>4))];
                    short8 aj = ebv[C32(r*16+l15, 16+(ks<<2)+(lane>>4))];
                    mi[r] = mfma16(ai, bm[ks], mi[r]);
                    mj[r] = mfma16(aj, bm[ks], mj[r]);
                }
            }
            float mb = meas_b[kk*128 + (w<<4) + l15];
            #pragma unroll
            for (int r=0;r<4;r++){
                #pragma unroll
                for (int j=0;j<4;j++)
                    qm[r][j] += 0.25f*(mi[r][j]+mb)*(mj[r][j]+mb);
            }
        }
    }
    __syncthreads();   // all reads of xin (V phase) complete before overwrite

    // ---- write msg-in (qm+measured) as bf16 into msgb (overlaps xin) ----
    short* msgb = &xin[0][0];   // [64][128] swizzled
    {
        const int col = (w<<4) + l15;
        #pragma unroll
        for (int r=0;r<4;r++){
            #pragma unroll
            for (int j=0;j<4;j++){
                int row = r*16 + lj + j;
                msgb[(C16(row, col>>3)<<3) + (col&7)] = f2bf(qm[r][j]);
            }
        }
    }
    __syncthreads();

    // ---- Phase OUT: msg = msgb@Wo^T + out_b; atomic scatter by tgt ----
    {
        const short8* mv = (const short8*)msgb;
        f32x4 ao[4];
        #pragma unroll
        for (int r=0;r<4;r++) ao[r]=(f32x4){0,0,0,0};
        #pragma unroll
        for (int ks=0; ks<4; ks++){
            short8 bo = bfrag(wO,128,w,ks,lane);
            #pragma unroll
            for (int r=0;r<4;r++){
                short8 a = mv[C16(r*16+l15, (ks<<2)+(lane>>4))];
                ao[r] = mfma16(a, bo, ao[r]);
            }
        }
        const int col = (w<<4) + l15;
        float ob = out_b[col];
        #pragma unroll
        for (int r=0;r<4;r++){
            #pragma unroll
            for (int j=0;j<4;j++){
                int row = r*16 + lj + j;
                if (e0 + row < EE)
                    atomicAdd(&agg[(long)tg[row]*128 + col], ao[r][j] + ob);
            }
        }
    }
}

// ---------------- Stage 3: LN + exact gelu, in place on d_out ----------------
__global__ __launch_bounds__(256) void final_kernel(
    const float* __restrict__ g2, const float* __restrict__ b2,
    float* __restrict__ io)
{
    const int lane = threadIdx.x & 63;
    const int n = blockIdx.x*4 + (threadIdx.x>>6);
    float v0 = io[(long)n*128 + lane];
    float v1 = io[(long)n*128 + 64 + lane];
    float s = v0+v1, sq = v0*v0 + v1*v1;
    #pragma unroll
    for (int m=1;m<64;m<<=1){ s += __shfl_xor(s,m); sq += __shfl_xor(sq,m); }
    float mean = s*(1.0f/128.0f);
    float rstd = rsqrtf(sq*(1.0f/128.0f)-mean*mean+1e-5f);
    float y0 = (v0-mean)*rstd*g2[lane]    + b2[lane];
    float y1 = (v1-mean)*rstd*g2[64+lane] + b2[64+lane];
    io[(long)n*128+lane]    = 0.5f*y0*(1.0f+erff(y0*0.70710678118f));
    io[(long)n*128+64+lane] = 0.5f*y1*(1.0f+erff(y1*0.70710678118f));
}

extern "C" void kernel_launch(void* const* d_in, const int* in_sizes, int n_in,
                              void* d_out, int out_size, void* d_ws, size_t ws_size,
                              hipStream_t stream)
{
    const float* x      = (const float*)d_in[0];
    const int*   eidx   = (const int*)  d_in[1];
    const float* sp_w   = (const float*)d_in[2];
    const float* sp_b   = (const float*)d_in[3];
    const float* ln1_g  = (const float*)d_in[4];
    const float* ln1_b  = (const float*)d_in[5];
    const float* pg     = (const float*)d_in[6];
    const float* amp_w  = (const float*)d_in[7];
    const float* amp_b  = (const float*)d_in[8];
    const float* ph_w   = (const float*)d_in[9];
    const float* ph_b   = (const float*)d_in[10];
    const float* ent_w  = (const float*)d_in[11];
    const float* ent_b  = (const float*)d_in[12];
    const float* q_w    = (const float*)d_in[13];
    const float* q_b    = (const float*)d_in[14];
    const float* k_w    = (const float*)d_in[15];
    const float* k_b    = (const float*)d_in[16];
    const float* v_w    = (const float*)d_in[17];
    const float* v_b    = (const float*)d_in[18];
    const float* meas_w = (const float*)d_in[19];
    const float* meas_b = (const float*)d_in[20];
    const float* out_w  = (const float*)d_in[21];
    const float* out_b  = (const float*)d_in[22];
    const float* ln2_g  = (const float*)d_in[23];
    const float* ln2_b  = (const float*)d_in[24];

    short* ws16 = (short*)d_ws;
    short* qfb  = ws16;                           // N*128 bf16 = 25.6 MB
    short* wAll = ws16 + (size_t)NN*128;
    short* wE = wAll;                             // 256*256
    short* wQ = wE + 65536;                       // 128*128
    short* wK = wQ + 16384;
    short* wV = wK + 16384;
    short* wM = wV + 16384;                       // 4*128*128
    short* wO = wM + 65536;

    float* agg = (float*)d_out;

    hipMemsetAsync(d_out, 0, (size_t)NN*128*sizeof(float), stream);
    prep_kernel<<<768, 256, 0, stream>>>(ent_w, q_w, k_w, v_w, meas_w, out_w, wAll);
    node_kernel<<<NN/2, 256, 0, stream>>>(x, sp_w, sp_b, ln1_g, ln1_b, pg,
                                          amp_w, amp_b, ph_w, ph_b, qfb);
    edge_kernel<<<(EE + ET - 1)/ET, 512, 0, stream>>>(qfb, eidx,
                                           wE, ent_b, wQ, q_b, wK, k_b, wV, v_b,
                                           wM, meas_b, wO, out_b, agg);
    final_kernel<<<NN/4, 256, 0, stream>>>(ln2_g, ln2_b, agg);
}